// Round 7
// baseline (276.159 us; speedup 1.0000x reference)
//
#include <hip/hip_runtime.h>
#include <math.h>

#define N_NODES 50000
#define E_EDGES 500000
#define P_PAIRS 200000
#define MAX_DEG 64    // Binomial(500k,1/50k): P(deg>=64) ~ 1e-28 per node

#define NB        196   // buckets: bucket(d) = d >> 8 (256 nodes each)
#define EB        2048  // edges per sort block
#define EPT       8     // edges per thread (256 thr)
#define SORT_BLKS 245   // ceil(500000/2048)

typedef __bf16    bf16x8 __attribute__((ext_vector_type(8)));
typedef __bf16    bf16x4 __attribute__((ext_vector_type(4)));
typedef _Float16  f16x8  __attribute__((ext_vector_type(8)));
typedef float     f32x4  __attribute__((ext_vector_type(4)));

// ---------------- K1: bucket-count  ||  conv_x  ||  weight pack ----------------

#define CONV_BLKS 1563   // ceil(N_NODES*128/4 / 1024): 4 float4 per thread
#define PREP_BLKS 128    // 32768/256

__global__ __launch_bounds__(256) void pre_k(
        const float* __restrict__ x, __bf16* __restrict__ xb,
        const int* __restrict__ dst,
        int* __restrict__ bucketCnt, int* __restrict__ blockBase,
        const float* __restrict__ Wl1, const float* __restrict__ Wr1,
        const float* __restrict__ Wl2, const float* __restrict__ Wr2,
        const float* __restrict__ W3,
        __bf16* __restrict__ P1, __bf16* __restrict__ P2, __bf16* __restrict__ P4) {
    __shared__ int cnt[NB];
    int b = blockIdx.x, t = threadIdx.x;
    if (b < SORT_BLKS) {
        if (t < NB) cnt[t] = 0;
        __syncthreads();
        int ebase = b * EB;
        #pragma unroll
        for (int i = 0; i < EPT; ++i) {
            int e = ebase + i * 256 + t;
            if (e < E_EDGES) atomicAdd(&cnt[dst[e] >> 8], 1);
        }
        __syncthreads();
        if (t < NB) blockBase[b * NB + t] = atomicAdd(&bucketCnt[t], cnt[t]);
    } else if (b < SORT_BLKS + CONV_BLKS) {
        int i0 = (b - SORT_BLKS) * 1024 + t;      // float4 index, 4 per thread
        #pragma unroll
        for (int k = 0; k < 4; ++k) {
            int i = i0 + k * 256;
            if (i < N_NODES * 128 / 4) {
                float4 v = ((const float4*)x)[i];
                bf16x4 o;
                o[0] = (__bf16)v.x; o[1] = (__bf16)v.y;
                o[2] = (__bf16)v.z; o[3] = (__bf16)v.w;
                *(bf16x4*)(xb + (size_t)i * 4) = o;   // single 8B store
            }
        }
    } else {
        int i = (b - SORT_BLKS - CONV_BLKS) * 256 + t;   // 0..32767
        int lane = (i >> 3) & 63;
        int j = i & 7;
        int kq = (lane >> 4) * 8 + j;
        {   // P1/P2: K=256 layout
            int kt = i >> 12, nt = (i >> 9) & 7;
            int n = nt * 16 + (lane & 15);
            int k = kt * 32 + kq;
            P1[i] = (__bf16)((k < 128) ? Wl1[n * 128 + k] : Wr1[n * 128 + (k - 128)]);
            P2[i] = (__bf16)((k < 128) ? Wl2[n * 128 + k] : Wr2[n * 128 + (k - 128)]);
        }
        {   // P4: K=128, N=256 layout
            int kt = i >> 13, nt = (i >> 9) & 15;
            int n = nt * 16 + (lane & 15);
            int k = kt * 32 + kq;
            P4[i] = (__bf16)((n < 128) ? W3[n * 256 + k] : W3[(n - 128) * 256 + 128 + k]);
        }
    }
}

// ---------------- K2: place edges into bucket-sorted edgebuf (staged in LDS) ----------------

__global__ __launch_bounds__(256) void place_k(const int* __restrict__ src,
                                               const int* __restrict__ dst,
                                               const int* __restrict__ bucketCnt,
                                               const int* __restrict__ blockBase,
                                               unsigned* __restrict__ edgebuf) {
    __shared__ int cnt[256];
    __shared__ int buf[256];
    __shared__ int sbase[NB];
    __shared__ int gbase[NB];
    __shared__ int cur[NB];
    __shared__ unsigned sortbuf[EB];
    __shared__ unsigned char bktof[EB];
    int blk = blockIdx.x, t = threadIdx.x;

    // bucket base prefix (exclusive scan of bucketCnt)
    int bv = (t < NB) ? bucketCnt[t] : 0;
    buf[t] = bv;
    __syncthreads();
    for (int off = 1; off < 256; off <<= 1) {
        int xv = (t >= off) ? buf[t - off] : 0;
        __syncthreads();
        buf[t] += xv;
        __syncthreads();
    }
    if (t < NB) gbase[t] = (buf[t] - bv) + blockBase[blk * NB + t];
    cnt[t] = 0;
    if (t < NB) cur[t] = 0;
    __syncthreads();

    unsigned packed[EPT];
    int bk[EPT];
    int ebase = blk * EB;
    #pragma unroll
    for (int i = 0; i < EPT; ++i) {
        int e = ebase + i * 256 + t;
        if (e < E_EDGES) {
            int d = dst[e];
            packed[i] = ((unsigned)d << 16) | (unsigned)src[e];
            bk[i] = d >> 8;
            atomicAdd(&cnt[bk[i]], 1);
        } else bk[i] = -1;
    }
    __syncthreads();

    // block-local exclusive scan of cnt
    int v = cnt[t];
    buf[t] = v;
    __syncthreads();
    for (int off = 1; off < 256; off <<= 1) {
        int xv = (t >= off) ? buf[t - off] : 0;
        __syncthreads();
        buf[t] += xv;
        __syncthreads();
    }
    if (t < NB) sbase[t] = buf[t] - v;
    __syncthreads();

    #pragma unroll
    for (int i = 0; i < EPT; ++i) {
        if (bk[i] >= 0) {
            int p = sbase[bk[i]] + atomicAdd(&cur[bk[i]], 1);
            sortbuf[p] = packed[i];
            bktof[p] = (unsigned char)bk[i];
        }
    }
    __syncthreads();

    int nE = E_EDGES - ebase; if (nE > EB) nE = EB;
    for (int i = t; i < nE; i += 256) {
        int bb = bktof[i];
        edgebuf[gbase[bb] + (i - sbase[bb])] = sortbuf[i];
    }
}

// ---------------- K3: build slot rows per bucket in LDS, dense writeout ----------------

__global__ __launch_bounds__(256) void slots_k(const unsigned* __restrict__ edgebuf,
                                               const int* __restrict__ bucketCnt,
                                               unsigned short* __restrict__ slots,
                                               int* __restrict__ deg) {
    __shared__ unsigned short srow[256 * MAX_DEG];   // 32 KB
    __shared__ int cur[256];
    __shared__ int buf[256];
    __shared__ int sc[2];
    int b = blockIdx.x, t = threadIdx.x;

    int bv = (t < NB) ? bucketCnt[t] : 0;
    buf[t] = bv;
    cur[t] = 0;
    __syncthreads();
    for (int off = 1; off < 256; off <<= 1) {
        int xv = (t >= off) ? buf[t - off] : 0;
        __syncthreads();
        buf[t] += xv;
        __syncthreads();
    }
    if (t == b) { sc[0] = buf[t] - bv; sc[1] = bv; }
    __syncthreads();
    int base = sc[0], n = sc[1];

    for (int i = t; i < n; i += 256) {
        unsigned p = edgebuf[base + i];
        int dl = (p >> 16) & 255;
        int pos = atomicAdd(&cur[dl], 1);
        if (pos < MAX_DEG) srow[dl * MAX_DEG + pos] = (unsigned short)(p & 0xFFFFu);
    }
    __syncthreads();
    // dense 32KB writeout as dwordx4 (8 iterations instead of 32)
    const int4* sr16 = (const int4*)srow;
    int4* sl16 = (int4*)slots;
    int gbase16 = b * 2048;                          // 256 rows * 8 int4
    for (int i = t; i < 2048; i += 256) {
        int node = b * 256 + (i >> 3);
        if (node < N_NODES) sl16[gbase16 + i] = sr16[i];
    }
    int node = b * 256 + t;
    if (node < N_NODES) deg[node] = cur[t];
}

// ---------------- segment-mean aggregation: exact-count single-volley gathers ----------------
// Measured (R6 duplication): agg1+agg2 ~= 36us total -- at the L3 random-256B-segment wall
// (~7.1 TB/s effective for 128MB/layer of gather traffic). Considered at-ceiling.

__global__ __launch_bounds__(256) void agg1_k(const __bf16* __restrict__ feat,
                                              const int* __restrict__ deg_a,
                                              const unsigned short* __restrict__ slots,
                                              __bf16* __restrict__ agg) {
    int n = blockIdx.x * 4 + (threadIdx.x >> 6);
    if (n >= N_NODES) return;                 // wave-uniform exit (n uniform per wave)
    int lane = threadIdx.x & 63;
    int slot = lane >> 4, l = lane & 15;
    int deg = deg_a[n];
    int nit = (deg < MAX_DEG) ? deg : MAX_DEG;

    int ed = (int)slots[n * MAX_DEG + lane];  // all 64 entries, unconditional, coalesced u16

    float s[8];
    #pragma unroll
    for (int e = 0; e < 8; ++e) s[e] = 0.f;

    int nv = (nit + 3) >> 2;                  // gathers needed (wave-uniform), 3 for deg 9-12
    int it = slot;
    while (nv > 0) {
        int take = (nv < 4) ? nv : 4;         // wave-uniform
        int sn0 = 0, sn1 = 0, sn2 = 0, sn3 = 0;
        bf16x8 v0{}, v1{}, v2{}, v3{};
        // issue all gathers of this volley before any accumulate (independent, in flight together)
        sn0 = __builtin_amdgcn_ds_bpermute(it << 2, ed);
        v0 = *(const bf16x8*)(feat + (size_t)sn0 * 128 + l * 8);
        if (take > 1) {
            sn1 = __builtin_amdgcn_ds_bpermute((it + 4) << 2, ed);
            v1 = *(const bf16x8*)(feat + (size_t)sn1 * 128 + l * 8);
        }
        if (take > 2) {
            sn2 = __builtin_amdgcn_ds_bpermute((it + 8) << 2, ed);
            v2 = *(const bf16x8*)(feat + (size_t)sn2 * 128 + l * 8);
        }
        if (take > 3) {
            sn3 = __builtin_amdgcn_ds_bpermute((it + 12) << 2, ed);
            v3 = *(const bf16x8*)(feat + (size_t)sn3 * 128 + l * 8);
        }
        if (it < nit) {
            #pragma unroll
            for (int e = 0; e < 8; ++e) s[e] += (float)v0[e];
        }
        if (take > 1 && it + 4 < nit) {
            #pragma unroll
            for (int e = 0; e < 8; ++e) s[e] += (float)v1[e];
        }
        if (take > 2 && it + 8 < nit) {
            #pragma unroll
            for (int e = 0; e < 8; ++e) s[e] += (float)v2[e];
        }
        if (take > 3 && it + 12 < nit) {
            #pragma unroll
            for (int e = 0; e < 8; ++e) s[e] += (float)v3[e];
        }
        it += 16;
        nv -= take;
    }

    #pragma unroll
    for (int e = 0; e < 8; ++e) {
        s[e] += __shfl_xor(s[e], 16, 64);
        s[e] += __shfl_xor(s[e], 32, 64);
    }

    if (slot == 0) {
        float inv = 1.0f / fmaxf((float)deg, 1.0f);
        bf16x8 o;
        #pragma unroll
        for (int e = 0; e < 8; ++e) o[e] = (__bf16)(s[e] * inv);
        *(bf16x8*)(agg + (size_t)n * 128 + l * 8) = o;
    }
}

// ---------------- layer 1: out = relu([agg|feat] @ B + bias), 16 rows/wave ----------------

__global__ __launch_bounds__(256) void layer_mfma_k(const __bf16* __restrict__ agg,
                                                    const __bf16* __restrict__ feat,
                                                    const __bf16* __restrict__ wpack,
                                                    const float* __restrict__ bias,
                                                    __bf16* __restrict__ out) {
    int wave = threadIdx.x >> 6;
    int lane = threadIdx.x & 63;
    int m = lane & 15, quad = lane >> 4;
    int rbase = blockIdx.x * 64 + wave * 16;
    int r0 = rbase + m; if (r0 > N_NODES - 1) r0 = N_NODES - 1;

    f32x4 acc[8];
    #pragma unroll
    for (int nt = 0; nt < 8; ++nt) acc[nt] = (f32x4)0.f;

    #pragma unroll
    for (int kt = 0; kt < 8; ++kt) {
        const __bf16* src = (kt < 4) ? agg : feat;
        int ko = (kt & 3) * 32 + quad * 8;
        bf16x8 a0 = *(const bf16x8*)(src + (size_t)r0 * 128 + ko);
        const __bf16* wb = wpack + (size_t)kt * 4096 + lane * 8;
        #pragma unroll
        for (int nt = 0; nt < 8; ++nt) {
            bf16x8 b = *(const bf16x8*)(wb + nt * 512);
            acc[nt] = __builtin_amdgcn_mfma_f32_16x16x32_bf16(a0, b, acc[nt], 0, 0, 0);
        }
    }

    #pragma unroll
    for (int r = 0; r < 4; ++r) {
        int row = rbase + quad * 4 + r;
        if (row < N_NODES) {
            #pragma unroll
            for (int nt = 0; nt < 8; ++nt) {
                float v = acc[nt][r] + bias[nt * 16 + m];
                out[(size_t)row * 128 + nt * 16 + m] = (__bf16)fmaxf(v, 0.f);
            }
        }
    }
}

// ---------------- layer 2 + UV: h2 never hits global ----------------

__global__ __launch_bounds__(256) void layer2uv_k(const __bf16* __restrict__ agg,
                                                  const __bf16* __restrict__ feat,
                                                  const __bf16* __restrict__ wpack,
                                                  const float* __restrict__ bias,
                                                  const __bf16* __restrict__ wpack4,
                                                  _Float16* __restrict__ UV) {
    __shared__ __bf16 sh[4][16][136];   // 136: rows 16B-aligned (272 B)
    int wave = threadIdx.x >> 6;
    int lane = threadIdx.x & 63;
    int m = lane & 15, q = lane >> 4;
    int rbase = blockIdx.x * 64 + wave * 16;
    int r0 = rbase + m; if (r0 > N_NODES - 1) r0 = N_NODES - 1;

    f32x4 acc[8];
    #pragma unroll
    for (int nt = 0; nt < 8; ++nt) acc[nt] = (f32x4)0.f;

    #pragma unroll
    for (int kt = 0; kt < 8; ++kt) {
        const __bf16* src = (kt < 4) ? agg : feat;
        int ko = (kt & 3) * 32 + q * 8;
        bf16x8 a0 = *(const bf16x8*)(src + (size_t)r0 * 128 + ko);
        const __bf16* wb = wpack + (size_t)kt * 4096 + lane * 8;
        #pragma unroll
        for (int nt = 0; nt < 8; ++nt) {
            bf16x8 b = *(const bf16x8*)(wb + nt * 512);
            acc[nt] = __builtin_amdgcn_mfma_f32_16x16x32_bf16(a0, b, acc[nt], 0, 0, 0);
        }
    }

    // relu'd h2 tile -> wave-private LDS (C-layout scatter, within-wave only)
    #pragma unroll
    for (int rr = 0; rr < 4; ++rr)
        #pragma unroll
        for (int nt = 0; nt < 8; ++nt) {
            float v = acc[nt][rr] + bias[nt * 16 + m];
            sh[wave][q * 4 + rr][nt * 16 + m] = (__bf16)fmaxf(v, 0.f);
        }

    f32x4 acc2[16];
    #pragma unroll
    for (int nt = 0; nt < 16; ++nt) acc2[nt] = (f32x4)0.f;

    #pragma unroll
    for (int kt = 0; kt < 4; ++kt) {
        bf16x8 a = *(const bf16x8*)&sh[wave][m][kt * 32 + q * 8];
        const __bf16* wb = wpack4 + (size_t)kt * 8192 + lane * 8;
        #pragma unroll
        for (int nt = 0; nt < 16; ++nt) {
            bf16x8 b = *(const bf16x8*)(wb + nt * 512);
            acc2[nt] = __builtin_amdgcn_mfma_f32_16x16x32_bf16(a, b, acc2[nt], 0, 0, 0);
        }
    }

    #pragma unroll
    for (int rr = 0; rr < 4; ++rr) {
        int row = rbase + q * 4 + rr;
        if (row < N_NODES) {
            #pragma unroll
            for (int nt = 0; nt < 16; ++nt)
                UV[(size_t)row * 256 + nt * 16 + m] = (_Float16)acc2[nt][rr];
        }
    }
}

// ---------------- pair epilogue: sigmoid(relu(U[a]+V[b]+b3) . W4 + b4) ----------------

__global__ __launch_bounds__(256) void pair_ep_k(const _Float16* __restrict__ UV,
                                                 const int* __restrict__ pairs,
                                                 const float* __restrict__ b3,
                                                 const float* __restrict__ W4,
                                                 const float* __restrict__ b4,
                                                 float* __restrict__ out) {
    int t = threadIdx.x;
    int g = t >> 4, l = t & 15;
    int base = blockIdx.x * 64;

    float4 b3a = *(const float4*)(b3 + l * 8);
    float4 b3b = *(const float4*)(b3 + l * 8 + 4);
    float4 w4a = *(const float4*)(W4 + l * 8);
    float4 w4b = *(const float4*)(W4 + l * 8 + 4);
    float bb[8] = {b3a.x, b3a.y, b3a.z, b3a.w, b3b.x, b3b.y, b3b.z, b3b.w};
    float ww[8] = {w4a.x, w4a.y, w4a.z, w4a.w, w4b.x, w4b.y, w4b.z, w4b.w};
    float b4s = b4[0];

    int2 pr[4];
    #pragma unroll
    for (int i = 0; i < 4; ++i) pr[i] = ((const int2*)pairs)[base + i * 16 + g];

    f16x8 ua[4], vb[4];
    #pragma unroll
    for (int i = 0; i < 4; ++i) {
        ua[i] = *(const f16x8*)(UV + (size_t)pr[i].x * 256 + l * 8);
        vb[i] = *(const f16x8*)(UV + (size_t)pr[i].y * 256 + 128 + l * 8);
    }

    #pragma unroll
    for (int i = 0; i < 4; ++i) {
        float p = 0.f;
        #pragma unroll
        for (int e = 0; e < 8; ++e)
            p += fmaxf((float)ua[i][e] + (float)vb[i][e] + bb[e], 0.f) * ww[e];
        #pragma unroll
        for (int s = 1; s < 16; s <<= 1) p += __shfl_xor(p, s, 64);
        if (l == 0)
            out[base + i * 16 + g] = 1.0f / (1.0f + expf(-(p + b4s)));
    }
}

// ---------------- launch ----------------

extern "C" void kernel_launch(void* const* d_in, const int* in_sizes, int n_in,
                              void* d_out, int out_size, void* d_ws, size_t ws_size,
                              hipStream_t stream) {
    const float* x   = (const float*)d_in[0];
    const int*   ei  = (const int*)d_in[1];
    const int*   prs = (const int*)d_in[2];
    const float* Wl1 = (const float*)d_in[3];
    const float* Wr1 = (const float*)d_in[4];
    const float* b1  = (const float*)d_in[5];
    const float* Wl2 = (const float*)d_in[6];
    const float* Wr2 = (const float*)d_in[7];
    const float* b2  = (const float*)d_in[8];
    const float* W3  = (const float*)d_in[9];
    const float* b3  = (const float*)d_in[10];
    const float* W4  = (const float*)d_in[11];
    const float* b4  = (const float*)d_in[12];
    float* out = (float*)d_out;

    const int* srcv = ei;
    const int* dstv = ei + E_EDGES;

    char* ws = (char*)d_ws;
    size_t off = 0;
    auto alloc = [&](size_t bytes) -> void* {
        void* p = ws + off;
        off = (off + bytes + 255) & ~(size_t)255;
        return p;
    };
    int*            bucketCnt  = (int*)alloc(sizeof(int) * NB);
    int*            blockBase  = (int*)alloc(sizeof(int) * SORT_BLKS * NB);
    unsigned*       edgebuf    = (unsigned*)alloc(sizeof(unsigned) * E_EDGES);
    int*            deg        = (int*)alloc(sizeof(int) * N_NODES);
    unsigned short* slots      = (unsigned short*)alloc(sizeof(unsigned short) * (size_t)N_NODES * MAX_DEG + 512);
    __bf16*   P1     = (__bf16*)alloc(sizeof(__bf16) * 32768);
    __bf16*   P2     = (__bf16*)alloc(sizeof(__bf16) * 32768);
    __bf16*   P4     = (__bf16*)alloc(sizeof(__bf16) * 32768);
    __bf16*   xb     = (__bf16*)alloc(sizeof(__bf16) * (size_t)N_NODES * 128);
    __bf16*   aggb   = (__bf16*)alloc(sizeof(__bf16) * (size_t)N_NODES * 128);
    __bf16*   h1b    = (__bf16*)alloc(sizeof(__bf16) * (size_t)N_NODES * 128);
    _Float16* UV     = (_Float16*)alloc(sizeof(_Float16) * (size_t)N_NODES * 256);
    (void)ws_size; (void)in_sizes; (void)n_in; (void)out_size;

    hipMemsetAsync(bucketCnt, 0, sizeof(int) * NB, stream);

    // K1: bucket-count || conv_x || weight pack
    pre_k<<<SORT_BLKS + CONV_BLKS + PREP_BLKS, 256, 0, stream>>>(
        x, xb, dstv, bucketCnt, blockBase, Wl1, Wr1, Wl2, Wr2, W3, P1, P2, P4);
    // K2: place edges (bucket-sorted, coalesced; internal bucket scan)
    place_k<<<SORT_BLKS, 256, 0, stream>>>(srcv, dstv, bucketCnt, blockBase, edgebuf);
    // K3: build slot rows + deg (dense dwordx4 writes, LDS atomics only)
    slots_k<<<NB, 256, 0, stream>>>(edgebuf, bucketCnt, slots, deg);

    // layer 1 -- layer_mfma_k launched TWICE (idempotent): MEASUREMENT ROUND 2
    agg1_k<<<(N_NODES + 3) / 4, 256, 0, stream>>>(xb, deg, slots, aggb);
    layer_mfma_k<<<(N_NODES + 63) / 64, 256, 0, stream>>>(aggb, xb, P1, b1, h1b);
    layer_mfma_k<<<(N_NODES + 63) / 64, 256, 0, stream>>>(aggb, xb, P1, b1, h1b);  // DUP
    // layer 2 + UV -- layer2uv_k launched TWICE
    agg1_k<<<(N_NODES + 3) / 4, 256, 0, stream>>>(h1b, deg, slots, aggb);
    layer2uv_k<<<(N_NODES + 63) / 64, 256, 0, stream>>>(aggb, h1b, P2, b2, P4, UV);
    layer2uv_k<<<(N_NODES + 63) / 64, 256, 0, stream>>>(aggb, h1b, P2, b2, P4, UV); // DUP
    // pair scoring -- launched TWICE
    pair_ep_k<<<P_PAIRS / 64, 256, 0, stream>>>(UV, prs, b3, W4, b4, out);
    pair_ep_k<<<P_PAIRS / 64, 256, 0, stream>>>(UV, prs, b3, W4, b4, out);          // DUP
}

// Round 8
// 246.911 us; speedup vs baseline: 1.1185x; 1.1185x over previous
//
#include <hip/hip_runtime.h>
#include <math.h>

#define N_NODES 50000
#define E_EDGES 500000
#define P_PAIRS 200000
#define MAX_DEG 64    // Binomial(500k,1/50k): P(deg>=64) ~ 1e-28 per node

#define NB        196   // buckets: bucket(d) = d >> 8 (256 nodes each)
#define EB        2048  // edges per sort block
#define EPT       8     // edges per thread (256 thr)
#define SORT_BLKS 245   // ceil(500000/2048)

typedef __bf16    bf16x8 __attribute__((ext_vector_type(8)));
typedef __bf16    bf16x4 __attribute__((ext_vector_type(4)));
typedef _Float16  f16x8  __attribute__((ext_vector_type(8)));
typedef float     f32x4  __attribute__((ext_vector_type(4)));

// ---------------- K1: bucket-count  ||  conv_x  ||  weight pack ----------------

#define CONV_BLKS 1563   // ceil(N_NODES*128/4 / 1024): 4 float4 per thread
#define PREP_BLKS 128    // 32768/256

__global__ __launch_bounds__(256) void pre_k(
        const float* __restrict__ x, __bf16* __restrict__ xb,
        const int* __restrict__ dst,
        int* __restrict__ bucketCnt, int* __restrict__ blockBase,
        const float* __restrict__ Wl1, const float* __restrict__ Wr1,
        const float* __restrict__ Wl2, const float* __restrict__ Wr2,
        const float* __restrict__ W3,
        __bf16* __restrict__ P1, __bf16* __restrict__ P2, __bf16* __restrict__ P4) {
    __shared__ int cnt[NB];
    int b = blockIdx.x, t = threadIdx.x;
    if (b < SORT_BLKS) {
        if (t < NB) cnt[t] = 0;
        __syncthreads();
        int ebase = b * EB;
        #pragma unroll
        for (int i = 0; i < EPT; ++i) {
            int e = ebase + i * 256 + t;
            if (e < E_EDGES) atomicAdd(&cnt[dst[e] >> 8], 1);
        }
        __syncthreads();
        if (t < NB) blockBase[b * NB + t] = atomicAdd(&bucketCnt[t], cnt[t]);
    } else if (b < SORT_BLKS + CONV_BLKS) {
        int i0 = (b - SORT_BLKS) * 1024 + t;      // float4 index, 4 per thread
        #pragma unroll
        for (int k = 0; k < 4; ++k) {
            int i = i0 + k * 256;
            if (i < N_NODES * 128 / 4) {
                float4 v = ((const float4*)x)[i];
                bf16x4 o;
                o[0] = (__bf16)v.x; o[1] = (__bf16)v.y;
                o[2] = (__bf16)v.z; o[3] = (__bf16)v.w;
                *(bf16x4*)(xb + (size_t)i * 4) = o;   // single 8B store
            }
        }
    } else {
        int i = (b - SORT_BLKS - CONV_BLKS) * 256 + t;   // 0..32767
        int lane = (i >> 3) & 63;
        int j = i & 7;
        int kq = (lane >> 4) * 8 + j;
        {   // P1/P2: K=256 layout
            int kt = i >> 12, nt = (i >> 9) & 7;
            int n = nt * 16 + (lane & 15);
            int k = kt * 32 + kq;
            P1[i] = (__bf16)((k < 128) ? Wl1[n * 128 + k] : Wr1[n * 128 + (k - 128)]);
            P2[i] = (__bf16)((k < 128) ? Wl2[n * 128 + k] : Wr2[n * 128 + (k - 128)]);
        }
        {   // P4: K=128, N=256 layout
            int kt = i >> 13, nt = (i >> 9) & 15;
            int n = nt * 16 + (lane & 15);
            int k = kt * 32 + kq;
            P4[i] = (__bf16)((n < 128) ? W3[n * 256 + k] : W3[(n - 128) * 256 + 128 + k]);
        }
    }
}

// ---------------- K2: place edges into bucket-sorted edgebuf (staged in LDS) ----------------

__global__ __launch_bounds__(256) void place_k(const int* __restrict__ src,
                                               const int* __restrict__ dst,
                                               const int* __restrict__ bucketCnt,
                                               const int* __restrict__ blockBase,
                                               unsigned* __restrict__ edgebuf) {
    __shared__ int cnt[256];
    __shared__ int buf[256];
    __shared__ int sbase[NB];
    __shared__ int gbase[NB];
    __shared__ int cur[NB];
    __shared__ unsigned sortbuf[EB];
    __shared__ unsigned char bktof[EB];
    int blk = blockIdx.x, t = threadIdx.x;

    // bucket base prefix (exclusive scan of bucketCnt)
    int bv = (t < NB) ? bucketCnt[t] : 0;
    buf[t] = bv;
    __syncthreads();
    for (int off = 1; off < 256; off <<= 1) {
        int xv = (t >= off) ? buf[t - off] : 0;
        __syncthreads();
        buf[t] += xv;
        __syncthreads();
    }
    if (t < NB) gbase[t] = (buf[t] - bv) + blockBase[blk * NB + t];
    cnt[t] = 0;
    if (t < NB) cur[t] = 0;
    __syncthreads();

    unsigned packed[EPT];
    int bk[EPT];
    int ebase = blk * EB;
    #pragma unroll
    for (int i = 0; i < EPT; ++i) {
        int e = ebase + i * 256 + t;
        if (e < E_EDGES) {
            int d = dst[e];
            packed[i] = ((unsigned)d << 16) | (unsigned)src[e];
            bk[i] = d >> 8;
            atomicAdd(&cnt[bk[i]], 1);
        } else bk[i] = -1;
    }
    __syncthreads();

    // block-local exclusive scan of cnt
    int v = cnt[t];
    buf[t] = v;
    __syncthreads();
    for (int off = 1; off < 256; off <<= 1) {
        int xv = (t >= off) ? buf[t - off] : 0;
        __syncthreads();
        buf[t] += xv;
        __syncthreads();
    }
    if (t < NB) sbase[t] = buf[t] - v;
    __syncthreads();

    #pragma unroll
    for (int i = 0; i < EPT; ++i) {
        if (bk[i] >= 0) {
            int p = sbase[bk[i]] + atomicAdd(&cur[bk[i]], 1);
            sortbuf[p] = packed[i];
            bktof[p] = (unsigned char)bk[i];
        }
    }
    __syncthreads();

    int nE = E_EDGES - ebase; if (nE > EB) nE = EB;
    for (int i = t; i < nE; i += 256) {
        int bb = bktof[i];
        edgebuf[gbase[bb] + (i - sbase[bb])] = sortbuf[i];
    }
}

// ---------------- K3: build slot rows per bucket in LDS, dense writeout ----------------

__global__ __launch_bounds__(256) void slots_k(const unsigned* __restrict__ edgebuf,
                                               const int* __restrict__ bucketCnt,
                                               unsigned short* __restrict__ slots,
                                               int* __restrict__ deg) {
    __shared__ unsigned short srow[256 * MAX_DEG];   // 32 KB
    __shared__ int cur[256];
    __shared__ int buf[256];
    __shared__ int sc[2];
    int b = blockIdx.x, t = threadIdx.x;

    int bv = (t < NB) ? bucketCnt[t] : 0;
    buf[t] = bv;
    cur[t] = 0;
    __syncthreads();
    for (int off = 1; off < 256; off <<= 1) {
        int xv = (t >= off) ? buf[t - off] : 0;
        __syncthreads();
        buf[t] += xv;
        __syncthreads();
    }
    if (t == b) { sc[0] = buf[t] - bv; sc[1] = bv; }
    __syncthreads();
    int base = sc[0], n = sc[1];

    for (int i = t; i < n; i += 256) {
        unsigned p = edgebuf[base + i];
        int dl = (p >> 16) & 255;
        int pos = atomicAdd(&cur[dl], 1);
        if (pos < MAX_DEG) srow[dl * MAX_DEG + pos] = (unsigned short)(p & 0xFFFFu);
    }
    __syncthreads();
    // dense 32KB writeout as dwordx4 (8 iterations instead of 32)
    const int4* sr16 = (const int4*)srow;
    int4* sl16 = (int4*)slots;
    int gbase16 = b * 2048;                          // 256 rows * 8 int4
    for (int i = t; i < 2048; i += 256) {
        int node = b * 256 + (i >> 3);
        if (node < N_NODES) sl16[gbase16 + i] = sr16[i];
    }
    int node = b * 256 + t;
    if (node < N_NODES) deg[node] = cur[t];
}

// ---------------- segment-mean aggregation: exact-count single-volley gathers ----------------
// Measured (R6 duplication): agg1+agg2 ~= 36us total. Considered at-ceiling.

__global__ __launch_bounds__(256) void agg1_k(const __bf16* __restrict__ feat,
                                              const int* __restrict__ deg_a,
                                              const unsigned short* __restrict__ slots,
                                              __bf16* __restrict__ agg) {
    int n = blockIdx.x * 4 + (threadIdx.x >> 6);
    if (n >= N_NODES) return;                 // wave-uniform exit (n uniform per wave)
    int lane = threadIdx.x & 63;
    int slot = lane >> 4, l = lane & 15;
    int deg = deg_a[n];
    int nit = (deg < MAX_DEG) ? deg : MAX_DEG;

    int ed = (int)slots[n * MAX_DEG + lane];  // all 64 entries, unconditional, coalesced u16

    float s[8];
    #pragma unroll
    for (int e = 0; e < 8; ++e) s[e] = 0.f;

    int nv = (nit + 3) >> 2;                  // gathers needed (wave-uniform), 3 for deg 9-12
    int it = slot;
    while (nv > 0) {
        int take = (nv < 4) ? nv : 4;         // wave-uniform
        int sn0 = 0, sn1 = 0, sn2 = 0, sn3 = 0;
        bf16x8 v0{}, v1{}, v2{}, v3{};
        // issue all gathers of this volley before any accumulate (independent, in flight together)
        sn0 = __builtin_amdgcn_ds_bpermute(it << 2, ed);
        v0 = *(const bf16x8*)(feat + (size_t)sn0 * 128 + l * 8);
        if (take > 1) {
            sn1 = __builtin_amdgcn_ds_bpermute((it + 4) << 2, ed);
            v1 = *(const bf16x8*)(feat + (size_t)sn1 * 128 + l * 8);
        }
        if (take > 2) {
            sn2 = __builtin_amdgcn_ds_bpermute((it + 8) << 2, ed);
            v2 = *(const bf16x8*)(feat + (size_t)sn2 * 128 + l * 8);
        }
        if (take > 3) {
            sn3 = __builtin_amdgcn_ds_bpermute((it + 12) << 2, ed);
            v3 = *(const bf16x8*)(feat + (size_t)sn3 * 128 + l * 8);
        }
        if (it < nit) {
            #pragma unroll
            for (int e = 0; e < 8; ++e) s[e] += (float)v0[e];
        }
        if (take > 1 && it + 4 < nit) {
            #pragma unroll
            for (int e = 0; e < 8; ++e) s[e] += (float)v1[e];
        }
        if (take > 2 && it + 8 < nit) {
            #pragma unroll
            for (int e = 0; e < 8; ++e) s[e] += (float)v2[e];
        }
        if (take > 3 && it + 12 < nit) {
            #pragma unroll
            for (int e = 0; e < 8; ++e) s[e] += (float)v3[e];
        }
        it += 16;
        nv -= take;
    }

    #pragma unroll
    for (int e = 0; e < 8; ++e) {
        s[e] += __shfl_xor(s[e], 16, 64);
        s[e] += __shfl_xor(s[e], 32, 64);
    }

    if (slot == 0) {
        float inv = 1.0f / fmaxf((float)deg, 1.0f);
        bf16x8 o;
        #pragma unroll
        for (int e = 0; e < 8; ++e) o[e] = (__bf16)(s[e] * inv);
        *(bf16x8*)(agg + (size_t)n * 128 + l * 8) = o;
    }
}

// ---------------- layer 1: out = relu([agg|feat] @ B + bias), 16 rows/wave ----------------

__global__ __launch_bounds__(256) void layer_mfma_k(const __bf16* __restrict__ agg,
                                                    const __bf16* __restrict__ feat,
                                                    const __bf16* __restrict__ wpack,
                                                    const float* __restrict__ bias,
                                                    __bf16* __restrict__ out) {
    int wave = threadIdx.x >> 6;
    int lane = threadIdx.x & 63;
    int m = lane & 15, quad = lane >> 4;
    int rbase = blockIdx.x * 64 + wave * 16;
    int r0 = rbase + m; if (r0 > N_NODES - 1) r0 = N_NODES - 1;

    f32x4 acc[8];
    #pragma unroll
    for (int nt = 0; nt < 8; ++nt) acc[nt] = (f32x4)0.f;

    #pragma unroll
    for (int kt = 0; kt < 8; ++kt) {
        const __bf16* src = (kt < 4) ? agg : feat;
        int ko = (kt & 3) * 32 + quad * 8;
        bf16x8 a0 = *(const bf16x8*)(src + (size_t)r0 * 128 + ko);
        const __bf16* wb = wpack + (size_t)kt * 4096 + lane * 8;
        #pragma unroll
        for (int nt = 0; nt < 8; ++nt) {
            bf16x8 b = *(const bf16x8*)(wb + nt * 512);
            acc[nt] = __builtin_amdgcn_mfma_f32_16x16x32_bf16(a0, b, acc[nt], 0, 0, 0);
        }
    }

    #pragma unroll
    for (int r = 0; r < 4; ++r) {
        int row = rbase + quad * 4 + r;
        if (row < N_NODES) {
            #pragma unroll
            for (int nt = 0; nt < 8; ++nt) {
                float v = acc[nt][r] + bias[nt * 16 + m];
                out[(size_t)row * 128 + nt * 16 + m] = (__bf16)fmaxf(v, 0.f);
            }
        }
    }
}

// ---------------- layer 2 + UV: h2 never hits global ----------------

__global__ __launch_bounds__(256) void layer2uv_k(const __bf16* __restrict__ agg,
                                                  const __bf16* __restrict__ feat,
                                                  const __bf16* __restrict__ wpack,
                                                  const float* __restrict__ bias,
                                                  const __bf16* __restrict__ wpack4,
                                                  _Float16* __restrict__ UV) {
    __shared__ __bf16 sh[4][16][136];   // 136: rows 16B-aligned (272 B)
    int wave = threadIdx.x >> 6;
    int lane = threadIdx.x & 63;
    int m = lane & 15, q = lane >> 4;
    int rbase = blockIdx.x * 64 + wave * 16;
    int r0 = rbase + m; if (r0 > N_NODES - 1) r0 = N_NODES - 1;

    f32x4 acc[8];
    #pragma unroll
    for (int nt = 0; nt < 8; ++nt) acc[nt] = (f32x4)0.f;

    #pragma unroll
    for (int kt = 0; kt < 8; ++kt) {
        const __bf16* src = (kt < 4) ? agg : feat;
        int ko = (kt & 3) * 32 + q * 8;
        bf16x8 a0 = *(const bf16x8*)(src + (size_t)r0 * 128 + ko);
        const __bf16* wb = wpack + (size_t)kt * 4096 + lane * 8;
        #pragma unroll
        for (int nt = 0; nt < 8; ++nt) {
            bf16x8 b = *(const bf16x8*)(wb + nt * 512);
            acc[nt] = __builtin_amdgcn_mfma_f32_16x16x32_bf16(a0, b, acc[nt], 0, 0, 0);
        }
    }

    // relu'd h2 tile -> wave-private LDS (C-layout scatter, within-wave only)
    #pragma unroll
    for (int rr = 0; rr < 4; ++rr)
        #pragma unroll
        for (int nt = 0; nt < 8; ++nt) {
            float v = acc[nt][rr] + bias[nt * 16 + m];
            sh[wave][q * 4 + rr][nt * 16 + m] = (__bf16)fmaxf(v, 0.f);
        }

    f32x4 acc2[16];
    #pragma unroll
    for (int nt = 0; nt < 16; ++nt) acc2[nt] = (f32x4)0.f;

    #pragma unroll
    for (int kt = 0; kt < 4; ++kt) {
        bf16x8 a = *(const bf16x8*)&sh[wave][m][kt * 32 + q * 8];
        const __bf16* wb = wpack4 + (size_t)kt * 8192 + lane * 8;
        #pragma unroll
        for (int nt = 0; nt < 16; ++nt) {
            bf16x8 b = *(const bf16x8*)(wb + nt * 512);
            acc2[nt] = __builtin_amdgcn_mfma_f32_16x16x32_bf16(a, b, acc2[nt], 0, 0, 0);
        }
    }

    #pragma unroll
    for (int rr = 0; rr < 4; ++rr) {
        int row = rbase + q * 4 + rr;
        if (row < N_NODES) {
            #pragma unroll
            for (int nt = 0; nt < 16; ++nt)
                UV[(size_t)row * 256 + nt * 16 + m] = (_Float16)acc2[nt][rr];
        }
    }
}

// ---------------- pair epilogue: sigmoid(relu(U[a]+V[b]+b3) . W4 + b4) ----------------

__global__ __launch_bounds__(256) void pair_ep_k(const _Float16* __restrict__ UV,
                                                 const int* __restrict__ pairs,
                                                 const float* __restrict__ b3,
                                                 const float* __restrict__ W4,
                                                 const float* __restrict__ b4,
                                                 float* __restrict__ out) {
    int t = threadIdx.x;
    int g = t >> 4, l = t & 15;
    int base = blockIdx.x * 64;

    float4 b3a = *(const float4*)(b3 + l * 8);
    float4 b3b = *(const float4*)(b3 + l * 8 + 4);
    float4 w4a = *(const float4*)(W4 + l * 8);
    float4 w4b = *(const float4*)(W4 + l * 8 + 4);
    float bb[8] = {b3a.x, b3a.y, b3a.z, b3a.w, b3b.x, b3b.y, b3b.z, b3b.w};
    float ww[8] = {w4a.x, w4a.y, w4a.z, w4a.w, w4b.x, w4b.y, w4b.z, w4b.w};
    float b4s = b4[0];

    int2 pr[4];
    #pragma unroll
    for (int i = 0; i < 4; ++i) pr[i] = ((const int2*)pairs)[base + i * 16 + g];

    f16x8 ua[4], vb[4];
    #pragma unroll
    for (int i = 0; i < 4; ++i) {
        ua[i] = *(const f16x8*)(UV + (size_t)pr[i].x * 256 + l * 8);
        vb[i] = *(const f16x8*)(UV + (size_t)pr[i].y * 256 + 128 + l * 8);
    }

    #pragma unroll
    for (int i = 0; i < 4; ++i) {
        float p = 0.f;
        #pragma unroll
        for (int e = 0; e < 8; ++e)
            p += fmaxf((float)ua[i][e] + (float)vb[i][e] + bb[e], 0.f) * ww[e];
        #pragma unroll
        for (int s = 1; s < 16; s <<= 1) p += __shfl_xor(p, s, 64);
        if (l == 0)
            out[base + i * 16 + g] = 1.0f / (1.0f + expf(-(p + b4s)));
    }
}

// ---------------- launch ----------------

extern "C" void kernel_launch(void* const* d_in, const int* in_sizes, int n_in,
                              void* d_out, int out_size, void* d_ws, size_t ws_size,
                              hipStream_t stream) {
    const float* x   = (const float*)d_in[0];
    const int*   ei  = (const int*)d_in[1];
    const int*   prs = (const int*)d_in[2];
    const float* Wl1 = (const float*)d_in[3];
    const float* Wr1 = (const float*)d_in[4];
    const float* b1  = (const float*)d_in[5];
    const float* Wl2 = (const float*)d_in[6];
    const float* Wr2 = (const float*)d_in[7];
    const float* b2  = (const float*)d_in[8];
    const float* W3  = (const float*)d_in[9];
    const float* b3  = (const float*)d_in[10];
    const float* W4  = (const float*)d_in[11];
    const float* b4  = (const float*)d_in[12];
    float* out = (float*)d_out;

    const int* srcv = ei;
    const int* dstv = ei + E_EDGES;

    char* ws = (char*)d_ws;
    size_t off = 0;
    auto alloc = [&](size_t bytes) -> void* {
        void* p = ws + off;
        off = (off + bytes + 255) & ~(size_t)255;
        return p;
    };
    int*            bucketCnt  = (int*)alloc(sizeof(int) * NB);
    int*            blockBase  = (int*)alloc(sizeof(int) * SORT_BLKS * NB);
    unsigned*       edgebuf    = (unsigned*)alloc(sizeof(unsigned) * E_EDGES);
    int*            deg        = (int*)alloc(sizeof(int) * N_NODES);
    unsigned short* slots      = (unsigned short*)alloc(sizeof(unsigned short) * (size_t)N_NODES * MAX_DEG + 512);
    __bf16*   P1     = (__bf16*)alloc(sizeof(__bf16) * 32768);
    __bf16*   P2     = (__bf16*)alloc(sizeof(__bf16) * 32768);
    __bf16*   P4     = (__bf16*)alloc(sizeof(__bf16) * 32768);
    __bf16*   xb     = (__bf16*)alloc(sizeof(__bf16) * (size_t)N_NODES * 128);
    __bf16*   aggb   = (__bf16*)alloc(sizeof(__bf16) * (size_t)N_NODES * 128);
    __bf16*   h1b    = (__bf16*)alloc(sizeof(__bf16) * (size_t)N_NODES * 128);
    _Float16* UV     = (_Float16*)alloc(sizeof(_Float16) * (size_t)N_NODES * 256);
    (void)ws_size; (void)in_sizes; (void)n_in; (void)out_size;

    // ---- preprocessing sequence, LAUNCHED TWICE (measurement #3) ----
    // Second pass re-zeros bucketCnt and recomputes everything; final state
    // identical-in-distribution (slot order permutes -- already tolerated).
    hipMemsetAsync(bucketCnt, 0, sizeof(int) * NB, stream);
    pre_k<<<SORT_BLKS + CONV_BLKS + PREP_BLKS, 256, 0, stream>>>(
        x, xb, dstv, bucketCnt, blockBase, Wl1, Wr1, Wl2, Wr2, W3, P1, P2, P4);
    place_k<<<SORT_BLKS, 256, 0, stream>>>(srcv, dstv, bucketCnt, blockBase, edgebuf);
    slots_k<<<NB, 256, 0, stream>>>(edgebuf, bucketCnt, slots, deg);

    hipMemsetAsync(bucketCnt, 0, sizeof(int) * NB, stream);                     // DUP
    pre_k<<<SORT_BLKS + CONV_BLKS + PREP_BLKS, 256, 0, stream>>>(               // DUP
        x, xb, dstv, bucketCnt, blockBase, Wl1, Wr1, Wl2, Wr2, W3, P1, P2, P4);
    place_k<<<SORT_BLKS, 256, 0, stream>>>(srcv, dstv, bucketCnt, blockBase, edgebuf); // DUP
    slots_k<<<NB, 256, 0, stream>>>(edgebuf, bucketCnt, slots, deg);            // DUP

    // layer 1
    agg1_k<<<(N_NODES + 3) / 4, 256, 0, stream>>>(xb, deg, slots, aggb);
    layer_mfma_k<<<(N_NODES + 63) / 64, 256, 0, stream>>>(aggb, xb, P1, b1, h1b);
    // layer 2 + UV (h2 stays in registers/LDS)
    agg1_k<<<(N_NODES + 3) / 4, 256, 0, stream>>>(h1b, deg, slots, aggb);
    layer2uv_k<<<(N_NODES + 63) / 64, 256, 0, stream>>>(aggb, h1b, P2, b2, P4, UV);
    // pair scoring
    pair_ep_k<<<P_PAIRS / 64, 256, 0, stream>>>(UV, prs, b3, W4, b4, out);
}

// Round 9
// 230.163 us; speedup vs baseline: 1.1998x; 1.0728x over previous
//
#include <hip/hip_runtime.h>
#include <math.h>

#define N_NODES 50000
#define E_EDGES 500000
#define P_PAIRS 200000
#define MAX_DEG 64    // Binomial(500k,1/50k): P(deg>=64) ~ 1e-28 per node

#define NB        196   // buckets: bucket(d) = d >> 8 (256 nodes each)
#define EB        2048  // edges per sort block
#define EPT       8     // edges per thread (256 thr)
#define SORT_BLKS 245   // ceil(500000/2048)

typedef __bf16    bf16x8 __attribute__((ext_vector_type(8)));
typedef __bf16    bf16x4 __attribute__((ext_vector_type(4)));
typedef _Float16  f16x8  __attribute__((ext_vector_type(8)));
typedef float     f32x4  __attribute__((ext_vector_type(4)));

// ---------------- K1: bucket-count  ||  conv_x  ||  weight pack ----------------

#define CONV_BLKS 1563   // ceil(N_NODES*128/4 / 1024): 4 float4 per thread
#define PREP_BLKS 128    // 32768/256

__global__ __launch_bounds__(256) void pre_k(
        const float* __restrict__ x, __bf16* __restrict__ xb,
        const int* __restrict__ dst,
        int* __restrict__ bucketCnt, int* __restrict__ blockBase,
        const float* __restrict__ Wl1, const float* __restrict__ Wr1,
        const float* __restrict__ Wl2, const float* __restrict__ Wr2,
        const float* __restrict__ W3,
        __bf16* __restrict__ P1, __bf16* __restrict__ P2, __bf16* __restrict__ P4) {
    __shared__ int cnt[NB];
    int b = blockIdx.x, t = threadIdx.x;
    if (b < SORT_BLKS) {
        if (t < NB) cnt[t] = 0;
        __syncthreads();
        int ebase = b * EB;
        #pragma unroll
        for (int i = 0; i < EPT; ++i) {
            int e = ebase + i * 256 + t;
            if (e < E_EDGES) atomicAdd(&cnt[dst[e] >> 8], 1);
        }
        __syncthreads();
        if (t < NB) blockBase[b * NB + t] = atomicAdd(&bucketCnt[t], cnt[t]);
    } else if (b < SORT_BLKS + CONV_BLKS) {
        int i0 = (b - SORT_BLKS) * 1024 + t;      // float4 index, 4 per thread
        #pragma unroll
        for (int k = 0; k < 4; ++k) {
            int i = i0 + k * 256;
            if (i < N_NODES * 128 / 4) {
                float4 v = ((const float4*)x)[i];
                bf16x4 o;
                o[0] = (__bf16)v.x; o[1] = (__bf16)v.y;
                o[2] = (__bf16)v.z; o[3] = (__bf16)v.w;
                *(bf16x4*)(xb + (size_t)i * 4) = o;   // single 8B store
            }
        }
    } else {
        int i = (b - SORT_BLKS - CONV_BLKS) * 256 + t;   // 0..32767
        int lane = (i >> 3) & 63;
        int j = i & 7;
        int kq = (lane >> 4) * 8 + j;
        {   // P1/P2: K=256 layout
            int kt = i >> 12, nt = (i >> 9) & 7;
            int n = nt * 16 + (lane & 15);
            int k = kt * 32 + kq;
            P1[i] = (__bf16)((k < 128) ? Wl1[n * 128 + k] : Wr1[n * 128 + (k - 128)]);
            P2[i] = (__bf16)((k < 128) ? Wl2[n * 128 + k] : Wr2[n * 128 + (k - 128)]);
        }
        {   // P4: K=128, N=256 layout
            int kt = i >> 13, nt = (i >> 9) & 15;
            int n = nt * 16 + (lane & 15);
            int k = kt * 32 + kq;
            P4[i] = (__bf16)((n < 128) ? W3[n * 256 + k] : W3[(n - 128) * 256 + 128 + k]);
        }
    }
}

// ---------------- K2: place edges into bucket-sorted edgebuf (staged in LDS) ----------------

__global__ __launch_bounds__(256) void place_k(const int* __restrict__ src,
                                               const int* __restrict__ dst,
                                               const int* __restrict__ bucketCnt,
                                               const int* __restrict__ blockBase,
                                               unsigned* __restrict__ edgebuf) {
    __shared__ int cnt[256];
    __shared__ int buf[256];
    __shared__ int sbase[NB];
    __shared__ int gbase[NB];
    __shared__ int cur[NB];
    __shared__ unsigned sortbuf[EB];
    __shared__ unsigned char bktof[EB];
    int blk = blockIdx.x, t = threadIdx.x;

    // bucket base prefix (exclusive scan of bucketCnt)
    int bv = (t < NB) ? bucketCnt[t] : 0;
    buf[t] = bv;
    __syncthreads();
    for (int off = 1; off < 256; off <<= 1) {
        int xv = (t >= off) ? buf[t - off] : 0;
        __syncthreads();
        buf[t] += xv;
        __syncthreads();
    }
    if (t < NB) gbase[t] = (buf[t] - bv) + blockBase[blk * NB + t];
    cnt[t] = 0;
    if (t < NB) cur[t] = 0;
    __syncthreads();

    unsigned packed[EPT];
    int bk[EPT];
    int ebase = blk * EB;
    #pragma unroll
    for (int i = 0; i < EPT; ++i) {
        int e = ebase + i * 256 + t;
        if (e < E_EDGES) {
            int d = dst[e];
            packed[i] = ((unsigned)d << 16) | (unsigned)src[e];
            bk[i] = d >> 8;
            atomicAdd(&cnt[bk[i]], 1);
        } else bk[i] = -1;
    }
    __syncthreads();

    // block-local exclusive scan of cnt
    int v = cnt[t];
    buf[t] = v;
    __syncthreads();
    for (int off = 1; off < 256; off <<= 1) {
        int xv = (t >= off) ? buf[t - off] : 0;
        __syncthreads();
        buf[t] += xv;
        __syncthreads();
    }
    if (t < NB) sbase[t] = buf[t] - v;
    __syncthreads();

    #pragma unroll
    for (int i = 0; i < EPT; ++i) {
        if (bk[i] >= 0) {
            int p = sbase[bk[i]] + atomicAdd(&cur[bk[i]], 1);
            sortbuf[p] = packed[i];
            bktof[p] = (unsigned char)bk[i];
        }
    }
    __syncthreads();

    int nE = E_EDGES - ebase; if (nE > EB) nE = EB;
    for (int i = t; i < nE; i += 256) {
        int bb = bktof[i];
        edgebuf[gbase[bb] + (i - sbase[bb])] = sortbuf[i];
    }
}

// ---------------- K3: build slot rows per bucket in LDS, dense writeout ----------------

__global__ __launch_bounds__(256) void slots_k(const unsigned* __restrict__ edgebuf,
                                               const int* __restrict__ bucketCnt,
                                               unsigned short* __restrict__ slots,
                                               int* __restrict__ deg) {
    __shared__ unsigned short srow[256 * MAX_DEG];   // 32 KB
    __shared__ int cur[256];
    __shared__ int buf[256];
    __shared__ int sc[2];
    int b = blockIdx.x, t = threadIdx.x;

    int bv = (t < NB) ? bucketCnt[t] : 0;
    buf[t] = bv;
    cur[t] = 0;
    __syncthreads();
    for (int off = 1; off < 256; off <<= 1) {
        int xv = (t >= off) ? buf[t - off] : 0;
        __syncthreads();
        buf[t] += xv;
        __syncthreads();
    }
    if (t == b) { sc[0] = buf[t] - bv; sc[1] = bv; }
    __syncthreads();
    int base = sc[0], n = sc[1];

    for (int i = t; i < n; i += 256) {
        unsigned p = edgebuf[base + i];
        int dl = (p >> 16) & 255;
        int pos = atomicAdd(&cur[dl], 1);
        if (pos < MAX_DEG) srow[dl * MAX_DEG + pos] = (unsigned short)(p & 0xFFFFu);
    }
    __syncthreads();
    // dense 32KB writeout as dwordx4 (8 iterations instead of 32)
    const int4* sr16 = (const int4*)srow;
    int4* sl16 = (int4*)slots;
    int gbase16 = b * 2048;                          // 256 rows * 8 int4
    for (int i = t; i < 2048; i += 256) {
        int node = b * 256 + (i >> 3);
        if (node < N_NODES) sl16[gbase16 + i] = sr16[i];
    }
    int node = b * 256 + t;
    if (node < N_NODES) deg[node] = cur[t];
}

// ---------------- segment-mean aggregation: exact-count single-volley gathers ----------------
// Measured (R6 duplication): agg1+agg2 ~= 36us total. At the L3 random-row wall. At-ceiling.

__global__ __launch_bounds__(256) void agg1_k(const __bf16* __restrict__ feat,
                                              const int* __restrict__ deg_a,
                                              const unsigned short* __restrict__ slots,
                                              __bf16* __restrict__ agg) {
    int n = blockIdx.x * 4 + (threadIdx.x >> 6);
    if (n >= N_NODES) return;                 // wave-uniform exit (n uniform per wave)
    int lane = threadIdx.x & 63;
    int slot = lane >> 4, l = lane & 15;
    int deg = deg_a[n];
    int nit = (deg < MAX_DEG) ? deg : MAX_DEG;

    int ed = (int)slots[n * MAX_DEG + lane];  // all 64 entries, unconditional, coalesced u16

    float s[8];
    #pragma unroll
    for (int e = 0; e < 8; ++e) s[e] = 0.f;

    int nv = (nit + 3) >> 2;                  // gathers needed (wave-uniform), 3 for deg 9-12
    int it = slot;
    while (nv > 0) {
        int take = (nv < 4) ? nv : 4;         // wave-uniform
        int sn0 = 0, sn1 = 0, sn2 = 0, sn3 = 0;
        bf16x8 v0{}, v1{}, v2{}, v3{};
        // issue all gathers of this volley before any accumulate (independent, in flight together)
        sn0 = __builtin_amdgcn_ds_bpermute(it << 2, ed);
        v0 = *(const bf16x8*)(feat + (size_t)sn0 * 128 + l * 8);
        if (take > 1) {
            sn1 = __builtin_amdgcn_ds_bpermute((it + 4) << 2, ed);
            v1 = *(const bf16x8*)(feat + (size_t)sn1 * 128 + l * 8);
        }
        if (take > 2) {
            sn2 = __builtin_amdgcn_ds_bpermute((it + 8) << 2, ed);
            v2 = *(const bf16x8*)(feat + (size_t)sn2 * 128 + l * 8);
        }
        if (take > 3) {
            sn3 = __builtin_amdgcn_ds_bpermute((it + 12) << 2, ed);
            v3 = *(const bf16x8*)(feat + (size_t)sn3 * 128 + l * 8);
        }
        if (it < nit) {
            #pragma unroll
            for (int e = 0; e < 8; ++e) s[e] += (float)v0[e];
        }
        if (take > 1 && it + 4 < nit) {
            #pragma unroll
            for (int e = 0; e < 8; ++e) s[e] += (float)v1[e];
        }
        if (take > 2 && it + 8 < nit) {
            #pragma unroll
            for (int e = 0; e < 8; ++e) s[e] += (float)v2[e];
        }
        if (take > 3 && it + 12 < nit) {
            #pragma unroll
            for (int e = 0; e < 8; ++e) s[e] += (float)v3[e];
        }
        it += 16;
        nv -= take;
    }

    #pragma unroll
    for (int e = 0; e < 8; ++e) {
        s[e] += __shfl_xor(s[e], 16, 64);
        s[e] += __shfl_xor(s[e], 32, 64);
    }

    if (slot == 0) {
        float inv = 1.0f / fmaxf((float)deg, 1.0f);
        bf16x8 o;
        #pragma unroll
        for (int e = 0; e < 8; ++e) o[e] = (__bf16)(s[e] * inv);
        *(bf16x8*)(agg + (size_t)n * 128 + l * 8) = o;
    }
}

// ---------------- layer 1: out = relu([agg|feat] @ B + bias), 32 rows/wave ----------------
// M=32 tiling: two 16-row A-fragments share every B-fragment load -> B traffic and wave
// count halve (B-stream through L1/L2 was the dominant modeled cost of this kernel).

__global__ __launch_bounds__(256) void layer_mfma_k(const __bf16* __restrict__ agg,
                                                    const __bf16* __restrict__ feat,
                                                    const __bf16* __restrict__ wpack,
                                                    const float* __restrict__ bias,
                                                    __bf16* __restrict__ out) {
    int wave = threadIdx.x >> 6;
    int lane = threadIdx.x & 63;
    int m = lane & 15, quad = lane >> 4;
    int rbase = blockIdx.x * 128 + wave * 32;
    int r0 = rbase + m;      if (r0 > N_NODES - 1) r0 = N_NODES - 1;
    int r1 = rbase + 16 + m; if (r1 > N_NODES - 1) r1 = N_NODES - 1;

    f32x4 acc[8][2];
    #pragma unroll
    for (int nt = 0; nt < 8; ++nt) { acc[nt][0] = (f32x4)0.f; acc[nt][1] = (f32x4)0.f; }

    #pragma unroll
    for (int kt = 0; kt < 8; ++kt) {
        const __bf16* src = (kt < 4) ? agg : feat;
        int ko = (kt & 3) * 32 + quad * 8;
        bf16x8 a0 = *(const bf16x8*)(src + (size_t)r0 * 128 + ko);
        bf16x8 a1 = *(const bf16x8*)(src + (size_t)r1 * 128 + ko);
        const __bf16* wb = wpack + (size_t)kt * 4096 + lane * 8;
        #pragma unroll
        for (int nt = 0; nt < 8; ++nt) {
            bf16x8 b = *(const bf16x8*)(wb + nt * 512);
            acc[nt][0] = __builtin_amdgcn_mfma_f32_16x16x32_bf16(a0, b, acc[nt][0], 0, 0, 0);
            acc[nt][1] = __builtin_amdgcn_mfma_f32_16x16x32_bf16(a1, b, acc[nt][1], 0, 0, 0);
        }
    }

    #pragma unroll
    for (int h = 0; h < 2; ++h)
        #pragma unroll
        for (int r = 0; r < 4; ++r) {
            int row = rbase + h * 16 + quad * 4 + r;
            if (row < N_NODES) {
                #pragma unroll
                for (int nt = 0; nt < 8; ++nt) {
                    float v = acc[nt][h][r] + bias[nt * 16 + m];
                    out[(size_t)row * 128 + nt * 16 + m] = (__bf16)fmaxf(v, 0.f);
                }
            }
        }
}

// ---------------- layer 2 + UV: h2 never hits global; M=32 rows/wave ----------------

__global__ __launch_bounds__(256) void layer2uv_k(const __bf16* __restrict__ agg,
                                                  const __bf16* __restrict__ feat,
                                                  const __bf16* __restrict__ wpack,
                                                  const float* __restrict__ bias,
                                                  const __bf16* __restrict__ wpack4,
                                                  _Float16* __restrict__ UV) {
    __shared__ __bf16 sh[4][32][136];   // 34816 B: 4 waves x 32 rows x 272B (16B-aligned)
    int wave = threadIdx.x >> 6;
    int lane = threadIdx.x & 63;
    int m = lane & 15, q = lane >> 4;
    int rbase = blockIdx.x * 128 + wave * 32;
    int r0 = rbase + m;      if (r0 > N_NODES - 1) r0 = N_NODES - 1;
    int r1 = rbase + 16 + m; if (r1 > N_NODES - 1) r1 = N_NODES - 1;

    f32x4 acc[8][2];
    #pragma unroll
    for (int nt = 0; nt < 8; ++nt) { acc[nt][0] = (f32x4)0.f; acc[nt][1] = (f32x4)0.f; }

    #pragma unroll
    for (int kt = 0; kt < 8; ++kt) {
        const __bf16* src = (kt < 4) ? agg : feat;
        int ko = (kt & 3) * 32 + q * 8;
        bf16x8 a0 = *(const bf16x8*)(src + (size_t)r0 * 128 + ko);
        bf16x8 a1 = *(const bf16x8*)(src + (size_t)r1 * 128 + ko);
        const __bf16* wb = wpack + (size_t)kt * 4096 + lane * 8;
        #pragma unroll
        for (int nt = 0; nt < 8; ++nt) {
            bf16x8 b = *(const bf16x8*)(wb + nt * 512);
            acc[nt][0] = __builtin_amdgcn_mfma_f32_16x16x32_bf16(a0, b, acc[nt][0], 0, 0, 0);
            acc[nt][1] = __builtin_amdgcn_mfma_f32_16x16x32_bf16(a1, b, acc[nt][1], 0, 0, 0);
        }
    }

    // relu'd h2 tile -> wave-private LDS (C-layout scatter, within-wave only)
    #pragma unroll
    for (int h = 0; h < 2; ++h)
        #pragma unroll
        for (int rr = 0; rr < 4; ++rr)
            #pragma unroll
            for (int nt = 0; nt < 8; ++nt) {
                float v = acc[nt][h][rr] + bias[nt * 16 + m];
                sh[wave][h * 16 + q * 4 + rr][nt * 16 + m] = (__bf16)fmaxf(v, 0.f);
            }

    f32x4 acc2[16][2];
    #pragma unroll
    for (int nt = 0; nt < 16; ++nt) { acc2[nt][0] = (f32x4)0.f; acc2[nt][1] = (f32x4)0.f; }

    #pragma unroll
    for (int kt = 0; kt < 4; ++kt) {
        bf16x8 a0 = *(const bf16x8*)&sh[wave][m][kt * 32 + q * 8];
        bf16x8 a1 = *(const bf16x8*)&sh[wave][16 + m][kt * 32 + q * 8];
        const __bf16* wb = wpack4 + (size_t)kt * 8192 + lane * 8;
        #pragma unroll
        for (int nt = 0; nt < 16; ++nt) {
            bf16x8 b = *(const bf16x8*)(wb + nt * 512);
            acc2[nt][0] = __builtin_amdgcn_mfma_f32_16x16x32_bf16(a0, b, acc2[nt][0], 0, 0, 0);
            acc2[nt][1] = __builtin_amdgcn_mfma_f32_16x16x32_bf16(a1, b, acc2[nt][1], 0, 0, 0);
        }
    }

    #pragma unroll
    for (int h = 0; h < 2; ++h)
        #pragma unroll
        for (int rr = 0; rr < 4; ++rr) {
            int row = rbase + h * 16 + q * 4 + rr;
            if (row < N_NODES) {
                #pragma unroll
                for (int nt = 0; nt < 16; ++nt)
                    UV[(size_t)row * 256 + nt * 16 + m] = (_Float16)acc2[nt][h][rr];
            }
        }
}

// ---------------- pair epilogue: sigmoid(relu(U[a]+V[b]+b3) . W4 + b4) ----------------

__global__ __launch_bounds__(256) void pair_ep_k(const _Float16* __restrict__ UV,
                                                 const int* __restrict__ pairs,
                                                 const float* __restrict__ b3,
                                                 const float* __restrict__ W4,
                                                 const float* __restrict__ b4,
                                                 float* __restrict__ out) {
    int t = threadIdx.x;
    int g = t >> 4, l = t & 15;
    int base = blockIdx.x * 64;

    float4 b3a = *(const float4*)(b3 + l * 8);
    float4 b3b = *(const float4*)(b3 + l * 8 + 4);
    float4 w4a = *(const float4*)(W4 + l * 8);
    float4 w4b = *(const float4*)(W4 + l * 8 + 4);
    float bb[8] = {b3a.x, b3a.y, b3a.z, b3a.w, b3b.x, b3b.y, b3b.z, b3b.w};
    float ww[8] = {w4a.x, w4a.y, w4a.z, w4a.w, w4b.x, w4b.y, w4b.z, w4b.w};
    float b4s = b4[0];

    int2 pr[4];
    #pragma unroll
    for (int i = 0; i < 4; ++i) pr[i] = ((const int2*)pairs)[base + i * 16 + g];

    f16x8 ua[4], vb[4];
    #pragma unroll
    for (int i = 0; i < 4; ++i) {
        ua[i] = *(const f16x8*)(UV + (size_t)pr[i].x * 256 + l * 8);
        vb[i] = *(const f16x8*)(UV + (size_t)pr[i].y * 256 + 128 + l * 8);
    }

    #pragma unroll
    for (int i = 0; i < 4; ++i) {
        float p = 0.f;
        #pragma unroll
        for (int e = 0; e < 8; ++e)
            p += fmaxf((float)ua[i][e] + (float)vb[i][e] + bb[e], 0.f) * ww[e];
        #pragma unroll
        for (int s = 1; s < 16; s <<= 1) p += __shfl_xor(p, s, 64);
        if (l == 0)
            out[base + i * 16 + g] = 1.0f / (1.0f + expf(-(p + b4s)));
    }
}

// ---------------- launch ----------------

extern "C" void kernel_launch(void* const* d_in, const int* in_sizes, int n_in,
                              void* d_out, int out_size, void* d_ws, size_t ws_size,
                              hipStream_t stream) {
    const float* x   = (const float*)d_in[0];
    const int*   ei  = (const int*)d_in[1];
    const int*   prs = (const int*)d_in[2];
    const float* Wl1 = (const float*)d_in[3];
    const float* Wr1 = (const float*)d_in[4];
    const float* b1  = (const float*)d_in[5];
    const float* Wl2 = (const float*)d_in[6];
    const float* Wr2 = (const float*)d_in[7];
    const float* b2  = (const float*)d_in[8];
    const float* W3  = (const float*)d_in[9];
    const float* b3  = (const float*)d_in[10];
    const float* W4  = (const float*)d_in[11];
    const float* b4  = (const float*)d_in[12];
    float* out = (float*)d_out;

    const int* srcv = ei;
    const int* dstv = ei + E_EDGES;

    char* ws = (char*)d_ws;
    size_t off = 0;
    auto alloc = [&](size_t bytes) -> void* {
        void* p = ws + off;
        off = (off + bytes + 255) & ~(size_t)255;
        return p;
    };
    int*            bucketCnt  = (int*)alloc(sizeof(int) * NB);
    int*            blockBase  = (int*)alloc(sizeof(int) * SORT_BLKS * NB);
    unsigned*       edgebuf    = (unsigned*)alloc(sizeof(unsigned) * E_EDGES);
    int*            deg        = (int*)alloc(sizeof(int) * N_NODES);
    unsigned short* slots      = (unsigned short*)alloc(sizeof(unsigned short) * (size_t)N_NODES * MAX_DEG + 512);
    __bf16*   P1     = (__bf16*)alloc(sizeof(__bf16) * 32768);
    __bf16*   P2     = (__bf16*)alloc(sizeof(__bf16) * 32768);
    __bf16*   P4     = (__bf16*)alloc(sizeof(__bf16) * 32768);
    __bf16*   xb     = (__bf16*)alloc(sizeof(__bf16) * (size_t)N_NODES * 128);
    __bf16*   aggb   = (__bf16*)alloc(sizeof(__bf16) * (size_t)N_NODES * 128);
    __bf16*   h1b    = (__bf16*)alloc(sizeof(__bf16) * (size_t)N_NODES * 128);
    _Float16* UV     = (_Float16*)alloc(sizeof(_Float16) * (size_t)N_NODES * 256);
    (void)ws_size; (void)in_sizes; (void)n_in; (void)out_size;

    hipMemsetAsync(bucketCnt, 0, sizeof(int) * NB, stream);

    // K1: bucket-count || conv_x || weight pack
    pre_k<<<SORT_BLKS + CONV_BLKS + PREP_BLKS, 256, 0, stream>>>(
        x, xb, dstv, bucketCnt, blockBase, Wl1, Wr1, Wl2, Wr2, W3, P1, P2, P4);
    // K2: place edges (bucket-sorted, coalesced; internal bucket scan)
    place_k<<<SORT_BLKS, 256, 0, stream>>>(srcv, dstv, bucketCnt, blockBase, edgebuf);
    // K3: build slot rows + deg (dense dwordx4 writes, LDS atomics only)
    slots_k<<<NB, 256, 0, stream>>>(edgebuf, bucketCnt, slots, deg);

    // layer 1 (M=32 tiles: 128 rows/block)
    agg1_k<<<(N_NODES + 3) / 4, 256, 0, stream>>>(xb, deg, slots, aggb);
    layer_mfma_k<<<(N_NODES + 127) / 128, 256, 0, stream>>>(aggb, xb, P1, b1, h1b);
    // layer 2 + UV (h2 stays in registers/LDS; M=32)
    agg1_k<<<(N_NODES + 3) / 4, 256, 0, stream>>>(h1b, deg, slots, aggb);
    layer2uv_k<<<(N_NODES + 127) / 128, 256, 0, stream>>>(aggb, h1b, P2, b2, P4, UV);
    // pair scoring
    pair_ep_k<<<P_PAIRS / 64, 256, 0, stream>>>(UV, prs, b3, W4, b4, out);
}

// Round 10
// 200.393 us; speedup vs baseline: 1.3781x; 1.1486x over previous
//
#include <hip/hip_runtime.h>
#include <math.h>

#define N_NODES 50000
#define E_EDGES 500000
#define P_PAIRS 200000
#define MAX_DEG 64    // Binomial(500k,1/50k): P(deg>=64) ~ 1e-28 per node

#define NB        196   // buckets: bucket(d) = d >> 8 (256 nodes each)
#define EB        2048  // edges per sort block
#define EPT       8     // edges per thread (256 thr)
#define SORT_BLKS 245   // ceil(500000/2048)

typedef __bf16    bf16x8 __attribute__((ext_vector_type(8)));
typedef __bf16    bf16x4 __attribute__((ext_vector_type(4)));
typedef _Float16  f16x8  __attribute__((ext_vector_type(8)));
typedef float     f32x4  __attribute__((ext_vector_type(4)));

// ---------------- K1: bucket-count  ||  conv_x  ||  weight pack ----------------

#define CONV_BLKS 1563   // ceil(N_NODES*128/4 / 1024): 4 float4 per thread
#define PREP_BLKS 128    // 32768/256

__global__ __launch_bounds__(256) void pre_k(
        const float* __restrict__ x, __bf16* __restrict__ xb,
        const int* __restrict__ dst,
        int* __restrict__ bucketCnt, int* __restrict__ blockBase,
        const float* __restrict__ Wl1, const float* __restrict__ Wr1,
        const float* __restrict__ Wl2, const float* __restrict__ Wr2,
        const float* __restrict__ W3,
        __bf16* __restrict__ P1, __bf16* __restrict__ P2, __bf16* __restrict__ P4) {
    __shared__ int cnt[NB];
    int b = blockIdx.x, t = threadIdx.x;
    if (b < SORT_BLKS) {
        if (t < NB) cnt[t] = 0;
        __syncthreads();
        int ebase = b * EB;
        #pragma unroll
        for (int i = 0; i < EPT; ++i) {
            int e = ebase + i * 256 + t;
            if (e < E_EDGES) atomicAdd(&cnt[dst[e] >> 8], 1);
        }
        __syncthreads();
        if (t < NB) blockBase[b * NB + t] = atomicAdd(&bucketCnt[t], cnt[t]);
    } else if (b < SORT_BLKS + CONV_BLKS) {
        int i0 = (b - SORT_BLKS) * 1024 + t;      // float4 index, 4 per thread
        #pragma unroll
        for (int k = 0; k < 4; ++k) {
            int i = i0 + k * 256;
            if (i < N_NODES * 128 / 4) {
                float4 v = ((const float4*)x)[i];
                bf16x4 o;
                o[0] = (__bf16)v.x; o[1] = (__bf16)v.y;
                o[2] = (__bf16)v.z; o[3] = (__bf16)v.w;
                *(bf16x4*)(xb + (size_t)i * 4) = o;   // single 8B store
            }
        }
    } else {
        int i = (b - SORT_BLKS - CONV_BLKS) * 256 + t;   // 0..32767
        int lane = (i >> 3) & 63;
        int j = i & 7;
        int kq = (lane >> 4) * 8 + j;
        {   // P1/P2: K=256 layout
            int kt = i >> 12, nt = (i >> 9) & 7;
            int n = nt * 16 + (lane & 15);
            int k = kt * 32 + kq;
            P1[i] = (__bf16)((k < 128) ? Wl1[n * 128 + k] : Wr1[n * 128 + (k - 128)]);
            P2[i] = (__bf16)((k < 128) ? Wl2[n * 128 + k] : Wr2[n * 128 + (k - 128)]);
        }
        {   // P4: K=128, N=256 layout
            int kt = i >> 13, nt = (i >> 9) & 15;
            int n = nt * 16 + (lane & 15);
            int k = kt * 32 + kq;
            P4[i] = (__bf16)((n < 128) ? W3[n * 256 + k] : W3[(n - 128) * 256 + 128 + k]);
        }
    }
}

// ---------------- K2: place edges into bucket-sorted edgebuf (staged in LDS) ----------------

__global__ __launch_bounds__(256) void place_k(const int* __restrict__ src,
                                               const int* __restrict__ dst,
                                               const int* __restrict__ bucketCnt,
                                               const int* __restrict__ blockBase,
                                               unsigned* __restrict__ edgebuf) {
    __shared__ int cnt[256];
    __shared__ int buf[256];
    __shared__ int sbase[NB];
    __shared__ int gbase[NB];
    __shared__ int cur[NB];
    __shared__ unsigned sortbuf[EB];
    __shared__ unsigned char bktof[EB];
    int blk = blockIdx.x, t = threadIdx.x;

    // bucket base prefix (exclusive scan of bucketCnt)
    int bv = (t < NB) ? bucketCnt[t] : 0;
    buf[t] = bv;
    __syncthreads();
    for (int off = 1; off < 256; off <<= 1) {
        int xv = (t >= off) ? buf[t - off] : 0;
        __syncthreads();
        buf[t] += xv;
        __syncthreads();
    }
    if (t < NB) gbase[t] = (buf[t] - bv) + blockBase[blk * NB + t];
    cnt[t] = 0;
    if (t < NB) cur[t] = 0;
    __syncthreads();

    unsigned packed[EPT];
    int bk[EPT];
    int ebase = blk * EB;
    #pragma unroll
    for (int i = 0; i < EPT; ++i) {
        int e = ebase + i * 256 + t;
        if (e < E_EDGES) {
            int d = dst[e];
            packed[i] = ((unsigned)d << 16) | (unsigned)src[e];
            bk[i] = d >> 8;
            atomicAdd(&cnt[bk[i]], 1);
        } else bk[i] = -1;
    }
    __syncthreads();

    // block-local exclusive scan of cnt
    int v = cnt[t];
    buf[t] = v;
    __syncthreads();
    for (int off = 1; off < 256; off <<= 1) {
        int xv = (t >= off) ? buf[t - off] : 0;
        __syncthreads();
        buf[t] += xv;
        __syncthreads();
    }
    if (t < NB) sbase[t] = buf[t] - v;
    __syncthreads();

    #pragma unroll
    for (int i = 0; i < EPT; ++i) {
        if (bk[i] >= 0) {
            int p = sbase[bk[i]] + atomicAdd(&cur[bk[i]], 1);
            sortbuf[p] = packed[i];
            bktof[p] = (unsigned char)bk[i];
        }
    }
    __syncthreads();

    int nE = E_EDGES - ebase; if (nE > EB) nE = EB;
    for (int i = t; i < nE; i += 256) {
        int bb = bktof[i];
        edgebuf[gbase[bb] + (i - sbase[bb])] = sortbuf[i];
    }
}

// ---------------- K3: build slot rows per bucket in LDS, dense writeout ----------------

__global__ __launch_bounds__(256) void slots_k(const unsigned* __restrict__ edgebuf,
                                               const int* __restrict__ bucketCnt,
                                               unsigned short* __restrict__ slots,
                                               int* __restrict__ deg) {
    __shared__ unsigned short srow[256 * MAX_DEG];   // 32 KB
    __shared__ int cur[256];
    __shared__ int buf[256];
    __shared__ int sc[2];
    int b = blockIdx.x, t = threadIdx.x;

    int bv = (t < NB) ? bucketCnt[t] : 0;
    buf[t] = bv;
    cur[t] = 0;
    __syncthreads();
    for (int off = 1; off < 256; off <<= 1) {
        int xv = (t >= off) ? buf[t - off] : 0;
        __syncthreads();
        buf[t] += xv;
        __syncthreads();
    }
    if (t == b) { sc[0] = buf[t] - bv; sc[1] = bv; }
    __syncthreads();
    int base = sc[0], n = sc[1];

    for (int i = t; i < n; i += 256) {
        unsigned p = edgebuf[base + i];
        int dl = (p >> 16) & 255;
        int pos = atomicAdd(&cur[dl], 1);
        if (pos < MAX_DEG) srow[dl * MAX_DEG + pos] = (unsigned short)(p & 0xFFFFu);
    }
    __syncthreads();
    // dense 32KB writeout as dwordx4
    const int4* sr16 = (const int4*)srow;
    int4* sl16 = (int4*)slots;
    int gbase16 = b * 2048;                          // 256 rows * 8 int4
    for (int i = t; i < 2048; i += 256) {
        int node = b * 256 + (i >> 3);
        if (node < N_NODES) sl16[gbase16 + i] = sr16[i];
    }
    int node = b * 256 + t;
    if (node < N_NODES) deg[node] = cur[t];
}

// ---------------- fused agg phase: 4 waves aggregate 16 nodes (4/wave, serial) into LDS ------
// R5's verified per-node volley structure, 1 wave per node. 12.5k waves total (full machine
// subscription -- fixes R1's 3128-wave starvation). Garbage slot entries beyond deg are safe:
// u16 index -> reads stay inside workspace (checked: xb/h1b + 16.78MB lands in h1b/UV).

__device__ __forceinline__ void agg_phase(const __bf16* __restrict__ feat,
                                          const int* __restrict__ deg_a,
                                          const unsigned short* __restrict__ slots,
                                          int rbase, int wave, int lane,
                                          __bf16 (* __restrict__ shA)[136]) {
    int slot = lane >> 4, l = lane & 15;
    int nb = rbase + wave * 4;
    int dv = deg_a[nb + (lane & 3)];          // lanes 0..3 carry this wave's 4 degrees
    int edv[4];
    #pragma unroll
    for (int i = 0; i < 4; ++i)
        edv[i] = (int)slots[(size_t)(nb + i) * MAX_DEG + lane];   // hoisted, coalesced u16

    #pragma unroll
    for (int i = 0; i < 4; ++i) {
        int deg = __shfl(dv, i, 64);
        int nit = (deg < MAX_DEG) ? deg : MAX_DEG;
        float s[8];
        #pragma unroll
        for (int e = 0; e < 8; ++e) s[e] = 0.f;

        int nv = (nit + 3) >> 2;              // wave-uniform
        int it = slot;
        while (nv > 0) {
            int take = (nv < 4) ? nv : 4;
            bf16x8 v0{}, v1{}, v2{}, v3{};
            int sn0 = __builtin_amdgcn_ds_bpermute(it << 2, edv[i]);
            v0 = *(const bf16x8*)(feat + (size_t)sn0 * 128 + l * 8);
            if (take > 1) {
                int sn1 = __builtin_amdgcn_ds_bpermute((it + 4) << 2, edv[i]);
                v1 = *(const bf16x8*)(feat + (size_t)sn1 * 128 + l * 8);
            }
            if (take > 2) {
                int sn2 = __builtin_amdgcn_ds_bpermute((it + 8) << 2, edv[i]);
                v2 = *(const bf16x8*)(feat + (size_t)sn2 * 128 + l * 8);
            }
            if (take > 3) {
                int sn3 = __builtin_amdgcn_ds_bpermute((it + 12) << 2, edv[i]);
                v3 = *(const bf16x8*)(feat + (size_t)sn3 * 128 + l * 8);
            }
            if (it < nit) {
                #pragma unroll
                for (int e = 0; e < 8; ++e) s[e] += (float)v0[e];
            }
            if (take > 1 && it + 4 < nit) {
                #pragma unroll
                for (int e = 0; e < 8; ++e) s[e] += (float)v1[e];
            }
            if (take > 2 && it + 8 < nit) {
                #pragma unroll
                for (int e = 0; e < 8; ++e) s[e] += (float)v2[e];
            }
            if (take > 3 && it + 12 < nit) {
                #pragma unroll
                for (int e = 0; e < 8; ++e) s[e] += (float)v3[e];
            }
            it += 16;
            nv -= take;
        }

        #pragma unroll
        for (int e = 0; e < 8; ++e) {
            s[e] += __shfl_xor(s[e], 16, 64);
            s[e] += __shfl_xor(s[e], 32, 64);
        }

        if (slot == 0) {
            float inv = 1.0f / fmaxf((float)deg, 1.0f);
            bf16x8 o;
            #pragma unroll
            for (int e = 0; e < 8; ++e) o[e] = (__bf16)(s[e] * inv);
            *(bf16x8*)&shA[wave * 4 + i][l * 8] = o;
        }
    }
}

// ---------------- fused layer 1: agg(16 nodes/block) -> LDS -> GEMM (N split across waves) ---
// Each B-fragment is read once per BLOCK (N-split), not once per wave: B traffic halves.
// aggb global round-trip eliminated.

__global__ __launch_bounds__(256) void fused_l1_k(const __bf16* __restrict__ feat,
                                                  const int* __restrict__ deg_a,
                                                  const unsigned short* __restrict__ slots,
                                                  const __bf16* __restrict__ wpack,
                                                  const float* __restrict__ bias,
                                                  __bf16* __restrict__ out) {
    __shared__ __bf16 shA[16][136];
    int wave = threadIdx.x >> 6;
    int lane = threadIdx.x & 63;
    int rbase = blockIdx.x * 16;

    agg_phase(feat, deg_a, slots, rbase, wave, lane, shA);
    __syncthreads();

    int m = lane & 15, quad = lane >> 4;
    int r0 = rbase + m;                       // grid exact: always < N_NODES
    f32x4 acc[2];
    acc[0] = (f32x4)0.f; acc[1] = (f32x4)0.f;

    #pragma unroll
    for (int kt = 0; kt < 8; ++kt) {
        bf16x8 a0;
        if (kt < 4) a0 = *(const bf16x8*)&shA[m][kt * 32 + quad * 8];
        else        a0 = *(const bf16x8*)(feat + (size_t)r0 * 128 + (kt & 3) * 32 + quad * 8);
        const __bf16* wb = wpack + (size_t)kt * 4096 + lane * 8;
        #pragma unroll
        for (int j = 0; j < 2; ++j) {
            int nt = wave * 2 + j;
            bf16x8 b = *(const bf16x8*)(wb + nt * 512);
            acc[j] = __builtin_amdgcn_mfma_f32_16x16x32_bf16(a0, b, acc[j], 0, 0, 0);
        }
    }

    #pragma unroll
    for (int j = 0; j < 2; ++j) {
        int nt = wave * 2 + j;
        #pragma unroll
        for (int r = 0; r < 4; ++r) {
            int row = rbase + quad * 4 + r;
            float v = acc[j][r] + bias[nt * 16 + m];
            out[(size_t)row * 128 + nt * 16 + m] = (__bf16)fmaxf(v, 0.f);
        }
    }
}

// ---------------- fused layer 2 + UV: agg -> LDS -> GEMM1 -> h2 LDS -> GEMM2 -> UV ----------

__global__ __launch_bounds__(256) void fused_l2_k(const __bf16* __restrict__ feat,
                                                  const int* __restrict__ deg_a,
                                                  const unsigned short* __restrict__ slots,
                                                  const __bf16* __restrict__ wpack,
                                                  const float* __restrict__ bias,
                                                  const __bf16* __restrict__ wpack4,
                                                  _Float16* __restrict__ UV) {
    __shared__ __bf16 shA[16][136];
    __shared__ __bf16 shH[16][136];
    int wave = threadIdx.x >> 6;
    int lane = threadIdx.x & 63;
    int rbase = blockIdx.x * 16;

    agg_phase(feat, deg_a, slots, rbase, wave, lane, shA);
    __syncthreads();

    int m = lane & 15, q = lane >> 4;
    int r0 = rbase + m;
    f32x4 acc[2];
    acc[0] = (f32x4)0.f; acc[1] = (f32x4)0.f;

    #pragma unroll
    for (int kt = 0; kt < 8; ++kt) {
        bf16x8 a0;
        if (kt < 4) a0 = *(const bf16x8*)&shA[m][kt * 32 + q * 8];
        else        a0 = *(const bf16x8*)(feat + (size_t)r0 * 128 + (kt & 3) * 32 + q * 8);
        const __bf16* wb = wpack + (size_t)kt * 4096 + lane * 8;
        #pragma unroll
        for (int j = 0; j < 2; ++j) {
            int nt = wave * 2 + j;
            bf16x8 b = *(const bf16x8*)(wb + nt * 512);
            acc[j] = __builtin_amdgcn_mfma_f32_16x16x32_bf16(a0, b, acc[j], 0, 0, 0);
        }
    }

    // relu'd h2 slice -> shared tile (each wave owns cols [wave*32, wave*32+32))
    #pragma unroll
    for (int j = 0; j < 2; ++j) {
        int nt = wave * 2 + j;
        #pragma unroll
        for (int rr = 0; rr < 4; ++rr) {
            float v = acc[j][rr] + bias[nt * 16 + m];
            shH[q * 4 + rr][nt * 16 + m] = (__bf16)fmaxf(v, 0.f);
        }
    }
    __syncthreads();

    f32x4 acc2[4];
    #pragma unroll
    for (int j = 0; j < 4; ++j) acc2[j] = (f32x4)0.f;

    #pragma unroll
    for (int kt = 0; kt < 4; ++kt) {
        bf16x8 a = *(const bf16x8*)&shH[m][kt * 32 + q * 8];
        const __bf16* wb = wpack4 + (size_t)kt * 8192 + lane * 8;
        #pragma unroll
        for (int j = 0; j < 4; ++j) {
            int nt = wave * 4 + j;
            bf16x8 b = *(const bf16x8*)(wb + nt * 512);
            acc2[j] = __builtin_amdgcn_mfma_f32_16x16x32_bf16(a, b, acc2[j], 0, 0, 0);
        }
    }

    #pragma unroll
    for (int j = 0; j < 4; ++j) {
        int nt = wave * 4 + j;
        #pragma unroll
        for (int rr = 0; rr < 4; ++rr) {
            int row = rbase + q * 4 + rr;
            UV[(size_t)row * 256 + nt * 16 + m] = (_Float16)acc2[j][rr];
        }
    }
}

// ---------------- pair epilogue: sigmoid(relu(U[a]+V[b]+b3) . W4 + b4) ----------------

__global__ __launch_bounds__(256) void pair_ep_k(const _Float16* __restrict__ UV,
                                                 const int* __restrict__ pairs,
                                                 const float* __restrict__ b3,
                                                 const float* __restrict__ W4,
                                                 const float* __restrict__ b4,
                                                 float* __restrict__ out) {
    int t = threadIdx.x;
    int g = t >> 4, l = t & 15;
    int base = blockIdx.x * 64;

    float4 b3a = *(const float4*)(b3 + l * 8);
    float4 b3b = *(const float4*)(b3 + l * 8 + 4);
    float4 w4a = *(const float4*)(W4 + l * 8);
    float4 w4b = *(const float4*)(W4 + l * 8 + 4);
    float bb[8] = {b3a.x, b3a.y, b3a.z, b3a.w, b3b.x, b3b.y, b3b.z, b3b.w};
    float ww[8] = {w4a.x, w4a.y, w4a.z, w4a.w, w4b.x, w4b.y, w4b.z, w4b.w};
    float b4s = b4[0];

    int2 pr[4];
    #pragma unroll
    for (int i = 0; i < 4; ++i) pr[i] = ((const int2*)pairs)[base + i * 16 + g];

    f16x8 ua[4], vb[4];
    #pragma unroll
    for (int i = 0; i < 4; ++i) {
        ua[i] = *(const f16x8*)(UV + (size_t)pr[i].x * 256 + l * 8);
        vb[i] = *(const f16x8*)(UV + (size_t)pr[i].y * 256 + 128 + l * 8);
    }

    #pragma unroll
    for (int i = 0; i < 4; ++i) {
        float p = 0.f;
        #pragma unroll
        for (int e = 0; e < 8; ++e)
            p += fmaxf((float)ua[i][e] + (float)vb[i][e] + bb[e], 0.f) * ww[e];
        #pragma unroll
        for (int s = 1; s < 16; s <<= 1) p += __shfl_xor(p, s, 64);
        if (l == 0)
            out[base + i * 16 + g] = 1.0f / (1.0f + expf(-(p + b4s)));
    }
}

// ---------------- launch ----------------

extern "C" void kernel_launch(void* const* d_in, const int* in_sizes, int n_in,
                              void* d_out, int out_size, void* d_ws, size_t ws_size,
                              hipStream_t stream) {
    const float* x   = (const float*)d_in[0];
    const int*   ei  = (const int*)d_in[1];
    const int*   prs = (const int*)d_in[2];
    const float* Wl1 = (const float*)d_in[3];
    const float* Wr1 = (const float*)d_in[4];
    const float* b1  = (const float*)d_in[5];
    const float* Wl2 = (const float*)d_in[6];
    const float* Wr2 = (const float*)d_in[7];
    const float* b2  = (const float*)d_in[8];
    const float* W3  = (const float*)d_in[9];
    const float* b3  = (const float*)d_in[10];
    const float* W4  = (const float*)d_in[11];
    const float* b4  = (const float*)d_in[12];
    float* out = (float*)d_out;

    const int* srcv = ei;
    const int* dstv = ei + E_EDGES;

    char* ws = (char*)d_ws;
    size_t off = 0;
    auto alloc = [&](size_t bytes) -> void* {
        void* p = ws + off;
        off = (off + bytes + 255) & ~(size_t)255;
        return p;
    };
    int*            bucketCnt  = (int*)alloc(sizeof(int) * NB);
    int*            blockBase  = (int*)alloc(sizeof(int) * SORT_BLKS * NB);
    unsigned*       edgebuf    = (unsigned*)alloc(sizeof(unsigned) * E_EDGES);
    int*            deg        = (int*)alloc(sizeof(int) * N_NODES);
    unsigned short* slots      = (unsigned short*)alloc(sizeof(unsigned short) * (size_t)N_NODES * MAX_DEG + 512);
    __bf16*   P1     = (__bf16*)alloc(sizeof(__bf16) * 32768);
    __bf16*   P2     = (__bf16*)alloc(sizeof(__bf16) * 32768);
    __bf16*   P4     = (__bf16*)alloc(sizeof(__bf16) * 32768);
    __bf16*   xb     = (__bf16*)alloc(sizeof(__bf16) * (size_t)N_NODES * 128);
    __bf16*   h1b    = (__bf16*)alloc(sizeof(__bf16) * (size_t)N_NODES * 128);
    _Float16* UV     = (_Float16*)alloc(sizeof(_Float16) * (size_t)N_NODES * 256);
    (void)ws_size; (void)in_sizes; (void)n_in; (void)out_size;

    hipMemsetAsync(bucketCnt, 0, sizeof(int) * NB, stream);

    // K1: bucket-count || conv_x || weight pack
    pre_k<<<SORT_BLKS + CONV_BLKS + PREP_BLKS, 256, 0, stream>>>(
        x, xb, dstv, bucketCnt, blockBase, Wl1, Wr1, Wl2, Wr2, W3, P1, P2, P4);
    // K2: place edges (bucket-sorted, coalesced; internal bucket scan)
    place_k<<<SORT_BLKS, 256, 0, stream>>>(srcv, dstv, bucketCnt, blockBase, edgebuf);
    // K3: build slot rows + deg (dense dwordx4 writes, LDS atomics only)
    slots_k<<<NB, 256, 0, stream>>>(edgebuf, bucketCnt, slots, deg);

    // fused layer 1: agg(16/block, 4/wave) + GEMM (agg never hits global)
    fused_l1_k<<<N_NODES / 16, 256, 0, stream>>>(xb, deg, slots, P1, b1, h1b);
    // fused layer 2 + UV
    fused_l2_k<<<N_NODES / 16, 256, 0, stream>>>(h1b, deg, slots, P2, b2, P4, UV);
    // pair scoring
    pair_ep_k<<<P_PAIRS / 64, 256, 0, stream>>>(UV, prs, b3, W4, b4, out);
}